// Round 1
// baseline (400.979 us; speedup 1.0000x reference)
//
#include <hip/hip_runtime.h>
#include <math.h>

#define NN 10000
#define NE 256000
#define HD 128
#define PD 64
#define NBASIS 8
#define NSPEC 10
#define RHID 64
#define RCUT 5.0f
#define INV_AVG 0.0390625f   // 1/25.6 exact
#define PI_F 3.14159265358979f

__device__ __forceinline__ float silu(float x) {
    return x / (1.0f + expf(-x));
}

// ---------------- zero accumulators + counter ----------------
__global__ void k_zero(float4* acc, int* cnt, long n4) {
    long i = (long)blockIdx.x * blockDim.x + threadIdx.x;
    if (i == 0) *cnt = 0;
    long stride = (long)gridDim.x * blockDim.x;
    float4 z = make_float4(0.f, 0.f, 0.f, 0.f);
    for (; i < n4; i += stride) acc[i] = z;
}

// ---------------- species id per node ----------------
__global__ void k_species(const float* __restrict__ na, int* __restrict__ spec) {
    int n = blockIdx.x * 256 + threadIdx.x;
    if (n >= NN) return;
    int s = 0;
    for (int k = 0; k < NSPEC; k++)
        if (na[n * NSPEC + k] > 0.5f) s = k;
    spec[n] = s;
}

// ---------------- per-species tables: sc0_s, h0_s ----------------
__global__ void k_tables(const float* __restrict__ We, const float* __restrict__ Wsc1,
                         const float* __restrict__ Wup01,
                         float* __restrict__ sc0s, float* __restrict__ h0s) {
    int t = blockIdx.x * 256 + threadIdx.x;
    if (t >= NSPEC * HD) return;
    int s = t / HD, h = t % HD;
    float acc1 = 0.f, acc2 = 0.f;
    for (int c = 0; c < HD; c++) {
        float fe = We[s * HD + c];
        acc1 += fe * Wsc1[(s * HD + c) * HD + h];
        acc2 += fe * Wup01[c * HD + h];
    }
    sc0s[t] = acc1;
    h0s[t] = acc2;
}

// ---------------- edge compaction: geometry + radial basis ----------------
__global__ void k_compact(const float* __restrict__ pos, const float* __restrict__ shifts,
                          const int* __restrict__ ii, const int* __restrict__ jj,
                          int* cnt, int* __restrict__ ai, int* __restrict__ aj,
                          float* __restrict__ aY, float* __restrict__ aF) {
    int e = blockIdx.x * 256 + threadIdx.x;
    if (e >= NE) return;
    int i = ii[e], j = jj[e];
    float vx = pos[i * 3 + 0] - pos[j * 3 + 0] - shifts[e * 3 + 0];
    float vy = pos[i * 3 + 1] - pos[j * 3 + 1] - shifts[e * 3 + 1];
    float vz = pos[i * 3 + 2] - pos[j * 3 + 2] - shifts[e * 3 + 2];
    float r = sqrtf(vx * vx + vy * vy + vz * vz);
    r = fmaxf(r, 1e-9f);
    if (r >= RCUT) return;   // env==0 exactly -> message exactly 0 -> skip
    int slot = atomicAdd(cnt, 1);
    ai[slot] = i; aj[slot] = j;
    float inv = 1.0f / r;
    aY[slot * 3 + 0] = vx * inv;
    aY[slot * 3 + 1] = vy * inv;
    aY[slot * 3 + 2] = vz * inv;
    float u = r * (1.0f / RCUT);
    float u5 = u * u * u * u * u;
    float env = 1.0f - 21.0f * u5 + 35.0f * u5 * u - 15.0f * u5 * u * u;
    float c0 = 0.6324555320336759f * env * inv;  // sqrt(2/RC)
    for (int b = 1; b <= NBASIS; b++)
        aF[slot * NBASIS + b - 1] = c0 * sinf((float)b * PI_F * r * (1.0f / RCUT));
}

// ---------------- layer-1 edge: radial MLP (wave-per-edge) + message scatter ----------------
__global__ __launch_bounds__(256) void k_edge1(
    const int* __restrict__ cnt, const int* __restrict__ ai, const int* __restrict__ aj,
    const float* __restrict__ aY, const float* __restrict__ aF, const int* __restrict__ spec,
    const float* __restrict__ R0, const float* __restrict__ R1,
    const float* __restrict__ R2, const float* __restrict__ R3,
    const float* __restrict__ h0s, float* __restrict__ a0, float* __restrict__ a1) {
    int lane = threadIdx.x & 63;
    int wid = (blockIdx.x * blockDim.x + threadIdx.x) >> 6;
    int nw = (gridDim.x * blockDim.x) >> 6;
    int nact = *cnt;
    for (int e = wid; e < nact; e += nw) {
        float x;
        {
            float acc = 0.f;
            #pragma unroll
            for (int b = 0; b < NBASIS; b++) acc += aF[e * NBASIS + b] * R0[b * RHID + lane];
            x = silu(acc);
        }
        {
            float acc = 0.f;
            for (int c = 0; c < RHID; c++) acc += __shfl(x, c) * R1[c * RHID + lane];
            x = silu(acc);
        }
        {
            float acc = 0.f;
            for (int c = 0; c < RHID; c++) acc += __shfl(x, c) * R2[c * RHID + lane];
            x = silu(acc);
        }
        float w00 = 0.f, w01 = 0.f, w10 = 0.f, w11 = 0.f;
        for (int c = 0; c < RHID; c++) {
            float xc = __shfl(x, c);
            const float* row = R3 + c * (2 * HD);
            w00 += xc * row[lane];
            w01 += xc * row[64 + lane];
            w10 += xc * row[128 + lane];
            w11 += xc * row[192 + lane];
        }
        int i = ai[e], j = aj[e];
        const float* h0 = h0s + spec[j] * HD;
        float Yx = aY[e * 3], Yy = aY[e * 3 + 1], Yz = aY[e * 3 + 2];
        float h0a = h0[lane], h0b = h0[64 + lane];
        float m0a = w00 * h0a * INV_AVG, m0b = w01 * h0b * INV_AVG;
        float m1a = w10 * h0a * INV_AVG, m1b = w11 * h0b * INV_AVG;
        atomicAdd(&a0[i * HD + lane], m0a);
        atomicAdd(&a0[i * HD + 64 + lane], m0b);
        atomicAdd(&a1[(i * HD + lane) * 3 + 0], m1a * Yx);
        atomicAdd(&a1[(i * HD + lane) * 3 + 1], m1a * Yy);
        atomicAdd(&a1[(i * HD + lane) * 3 + 2], m1a * Yz);
        atomicAdd(&a1[(i * HD + 64 + lane) * 3 + 0], m1b * Yx);
        atomicAdd(&a1[(i * HD + 64 + lane) * 3 + 1], m1b * Yy);
        atomicAdd(&a1[(i * HD + 64 + lane) * 3 + 2], m1b * Yz);
    }
}

// ---------------- nodeA: A0/A1 -> B0/B1 -> out0 (d_out half 0), out1 ----------------
__global__ __launch_bounds__(256) void k_nodeA(
    const float* __restrict__ a0, const float* __restrict__ a1, const int* __restrict__ spec,
    const float* __restrict__ Wout0, const float* __restrict__ Wout1,
    const float* __restrict__ Wp0, const float* __restrict__ Wp1,
    const float* __restrict__ Wl0, const float* __restrict__ Wl1,
    const float* __restrict__ sc0s, float* __restrict__ out0, float* __restrict__ out1) {
    __shared__ float sB0[4][PD];
    __shared__ float sB1[4][PD * 3];
    int w = threadIdx.x >> 6, lane = threadIdx.x & 63;
    int n = blockIdx.x * 4 + w;
    int p = lane;
    float A0 = 0.f, A1x = 0.f, A1y = 0.f, A1z = 0.f;
    const float* a0n = a0 + n * HD;
    const float* a1n = a1 + (size_t)n * HD * 3;
    for (int h = 0; h < HD; h++) {
        float w0 = Wout0[h * PD + p], w1 = Wout1[h * PD + p];
        A0 += a0n[h] * w0;
        A1x += a1n[h * 3 + 0] * w1;
        A1y += a1n[h * 3 + 1] * w1;
        A1z += a1n[h * 3 + 2] * w1;
    }
    float dot = A1x * A1x + A1y * A1y + A1z * A1z;
    int s = spec[n];
    const float* wp0 = Wp0 + (s * 5) * PD;
    float A02 = A0 * A0;
    float B0 = wp0[p] * A0 + wp0[PD + p] * A02 + wp0[2 * PD + p] * A02 * A0 +
               wp0[3 * PD + p] * dot + wp0[4 * PD + p] * A0 * dot;
    const float* wp1 = Wp1 + (s * 4) * PD;
    float fac = wp1[p] + wp1[PD + p] * A0 + wp1[2 * PD + p] * A02 + wp1[3 * PD + p] * dot;
    sB0[w][p] = B0;
    sB1[w][p * 3 + 0] = fac * A1x;
    sB1[w][p * 3 + 1] = fac * A1y;
    sB1[w][p * 3 + 2] = fac * A1z;
    __syncthreads();
    float o0a = 0.f, o0b = 0.f;
    float o1a0 = 0.f, o1a1 = 0.f, o1a2 = 0.f, o1b0 = 0.f, o1b1 = 0.f, o1b2 = 0.f;
    for (int q = 0; q < PD; q++) {
        float b0 = sB0[w][q];
        float b1x = sB1[w][q * 3], b1y = sB1[w][q * 3 + 1], b1z = sB1[w][q * 3 + 2];
        float wla = Wl0[q * HD + lane], wlb = Wl0[q * HD + 64 + lane];
        o0a += b0 * wla; o0b += b0 * wlb;
        float wma = Wl1[q * HD + lane], wmb = Wl1[q * HD + 64 + lane];
        o1a0 += b1x * wma; o1a1 += b1y * wma; o1a2 += b1z * wma;
        o1b0 += b1x * wmb; o1b1 += b1y * wmb; o1b2 += b1z * wmb;
    }
    const float* scs = sc0s + s * HD;
    out0[n * HD + lane] = o0a + scs[lane];
    out0[n * HD + 64 + lane] = o0b + scs[64 + lane];
    size_t base = ((size_t)n * HD + lane) * 3;
    out1[base + 0] = o1a0; out1[base + 1] = o1a1; out1[base + 2] = o1a2;
    size_t base2 = ((size_t)n * HD + 64 + lane) * 3;
    out1[base2 + 0] = o1b0; out1[base2 + 1] = o1b1; out1[base2 + 2] = o1b2;
}

// ---------------- nodeB: sc0b, g0, g1 ----------------
__global__ __launch_bounds__(256) void k_nodeB(
    const float* __restrict__ out0, const float* __restrict__ out1, const int* __restrict__ spec,
    const float* __restrict__ Wsc2, const float* __restrict__ Wup02, const float* __restrict__ Wup12,
    float* __restrict__ sc0b, float* __restrict__ g0, float* __restrict__ g1) {
    int w = threadIdx.x >> 6, lane = threadIdx.x & 63;
    int n = blockIdx.x * 4 + w;
    int s = spec[n];
    float sb_a = 0.f, sb_b = 0.f, g0a = 0.f, g0b = 0.f;
    float g1a0 = 0.f, g1a1 = 0.f, g1a2 = 0.f, g1b0 = 0.f, g1b1 = 0.f, g1b2 = 0.f;
    const float* o0 = out0 + n * HD;
    const float* o1 = out1 + (size_t)n * HD * 3;
    const float* Ws = Wsc2 + (size_t)s * HD * HD;
    for (int c = 0; c < HD; c++) {
        float v0 = o0[c];
        sb_a += v0 * Ws[c * HD + lane];
        sb_b += v0 * Ws[c * HD + 64 + lane];
        g0a += v0 * Wup02[c * HD + lane];
        g0b += v0 * Wup02[c * HD + 64 + lane];
        float w1a = Wup12[c * HD + lane], w1b = Wup12[c * HD + 64 + lane];
        float v1x = o1[c * 3], v1y = o1[c * 3 + 1], v1z = o1[c * 3 + 2];
        g1a0 += v1x * w1a; g1a1 += v1y * w1a; g1a2 += v1z * w1a;
        g1b0 += v1x * w1b; g1b1 += v1y * w1b; g1b2 += v1z * w1b;
    }
    sc0b[n * HD + lane] = sb_a;
    sc0b[n * HD + 64 + lane] = sb_b;
    g0[n * HD + lane] = g0a;
    g0[n * HD + 64 + lane] = g0b;
    size_t base = ((size_t)n * HD + lane) * 3;
    g1[base + 0] = g1a0; g1[base + 1] = g1a1; g1[base + 2] = g1a2;
    size_t base2 = ((size_t)n * HD + 64 + lane) * 3;
    g1[base2 + 0] = g1b0; g1[base2 + 1] = g1b1; g1[base2 + 2] = g1b2;
}

// ---------------- layer-2 edge ----------------
__global__ __launch_bounds__(256) void k_edge2(
    const int* __restrict__ cnt, const int* __restrict__ ai, const int* __restrict__ aj,
    const float* __restrict__ aY, const float* __restrict__ aF,
    const float* __restrict__ R0, const float* __restrict__ R1,
    const float* __restrict__ R2, const float* __restrict__ R3,
    const float* __restrict__ g0, const float* __restrict__ g1,
    float* __restrict__ a0, float* __restrict__ a1) {
    int lane = threadIdx.x & 63;
    int wid = (blockIdx.x * blockDim.x + threadIdx.x) >> 6;
    int nw = (gridDim.x * blockDim.x) >> 6;
    int nact = *cnt;
    for (int e = wid; e < nact; e += nw) {
        float x;
        {
            float acc = 0.f;
            #pragma unroll
            for (int b = 0; b < NBASIS; b++) acc += aF[e * NBASIS + b] * R0[b * RHID + lane];
            x = silu(acc);
        }
        {
            float acc = 0.f;
            for (int c = 0; c < RHID; c++) acc += __shfl(x, c) * R1[c * RHID + lane];
            x = silu(acc);
        }
        {
            float acc = 0.f;
            for (int c = 0; c < RHID; c++) acc += __shfl(x, c) * R2[c * RHID + lane];
            x = silu(acc);
        }
        float wa[5] = {0, 0, 0, 0, 0}, wb[5] = {0, 0, 0, 0, 0};
        for (int c = 0; c < RHID; c++) {
            float xc = __shfl(x, c);
            const float* row = R3 + c * (5 * HD);
            #pragma unroll
            for (int q = 0; q < 5; q++) {
                wa[q] += xc * row[q * HD + lane];
                wb[q] += xc * row[q * HD + 64 + lane];
            }
        }
        int i = ai[e], j = aj[e];
        float Yx = aY[e * 3], Yy = aY[e * 3 + 1], Yz = aY[e * 3 + 2];
        const float* g0j = g0 + j * HD;
        const float* g1j = g1 + (size_t)j * HD * 3;
        float ga = g0j[lane], gb = g0j[64 + lane];
        float gax = g1j[lane * 3], gay = g1j[lane * 3 + 1], gaz = g1j[lane * 3 + 2];
        float gbx = g1j[(64 + lane) * 3], gby = g1j[(64 + lane) * 3 + 1], gbz = g1j[(64 + lane) * 3 + 2];
        float dota = gax * Yx + gay * Yy + gaz * Yz;
        float dotb = gbx * Yx + gby * Yy + gbz * Yz;
        float m0a = (wa[0] * ga + wa[3] * dota) * INV_AVG;
        float m0b = (wb[0] * gb + wb[3] * dotb) * INV_AVG;
        float cax = gay * Yz - gaz * Yy, cay = gaz * Yx - gax * Yz, caz = gax * Yy - gay * Yx;
        float cbx = gby * Yz - gbz * Yy, cby = gbz * Yx - gbx * Yz, cbz = gbx * Yy - gby * Yx;
        float m1ax = (wa[1] * ga * Yx + wa[2] * gax + wa[4] * cax) * INV_AVG;
        float m1ay = (wa[1] * ga * Yy + wa[2] * gay + wa[4] * cay) * INV_AVG;
        float m1az = (wa[1] * ga * Yz + wa[2] * gaz + wa[4] * caz) * INV_AVG;
        float m1bx = (wb[1] * gb * Yx + wb[2] * gbx + wb[4] * cbx) * INV_AVG;
        float m1by = (wb[1] * gb * Yy + wb[2] * gby + wb[4] * cby) * INV_AVG;
        float m1bz = (wb[1] * gb * Yz + wb[2] * gbz + wb[4] * cbz) * INV_AVG;
        atomicAdd(&a0[i * HD + lane], m0a);
        atomicAdd(&a0[i * HD + 64 + lane], m0b);
        atomicAdd(&a1[(i * HD + lane) * 3 + 0], m1ax);
        atomicAdd(&a1[(i * HD + lane) * 3 + 1], m1ay);
        atomicAdd(&a1[(i * HD + lane) * 3 + 2], m1az);
        atomicAdd(&a1[(i * HD + 64 + lane) * 3 + 0], m1bx);
        atomicAdd(&a1[(i * HD + 64 + lane) * 3 + 1], m1by);
        atomicAdd(&a1[(i * HD + 64 + lane) * 3 + 2], m1bz);
    }
}

// ---------------- nodeC: final out0b (d_out half 1) ----------------
__global__ __launch_bounds__(256) void k_nodeC(
    const float* __restrict__ a0, const float* __restrict__ a1, const int* __restrict__ spec,
    const float* __restrict__ Wout0, const float* __restrict__ Wout1,
    const float* __restrict__ Wp0, const float* __restrict__ Wl0,
    const float* __restrict__ sc0b, float* __restrict__ outb) {
    __shared__ float sB0[4][PD];
    int w = threadIdx.x >> 6, lane = threadIdx.x & 63;
    int n = blockIdx.x * 4 + w;
    int p = lane;
    float A0 = 0.f, A1x = 0.f, A1y = 0.f, A1z = 0.f;
    const float* a0n = a0 + n * HD;
    const float* a1n = a1 + (size_t)n * HD * 3;
    for (int h = 0; h < HD; h++) {
        float w0 = Wout0[h * PD + p], w1 = Wout1[h * PD + p];
        A0 += a0n[h] * w0;
        A1x += a1n[h * 3 + 0] * w1;
        A1y += a1n[h * 3 + 1] * w1;
        A1z += a1n[h * 3 + 2] * w1;
    }
    float dot = A1x * A1x + A1y * A1y + A1z * A1z;
    int s = spec[n];
    const float* wp0 = Wp0 + (s * 5) * PD;
    float A02 = A0 * A0;
    float B0 = wp0[p] * A0 + wp0[PD + p] * A02 + wp0[2 * PD + p] * A02 * A0 +
               wp0[3 * PD + p] * dot + wp0[4 * PD + p] * A0 * dot;
    sB0[w][p] = B0;
    __syncthreads();
    float oa = 0.f, ob = 0.f;
    for (int q = 0; q < PD; q++) {
        float b0 = sB0[w][q];
        oa += b0 * Wl0[q * HD + lane];
        ob += b0 * Wl0[q * HD + 64 + lane];
    }
    outb[n * HD + lane] = oa + sc0b[n * HD + lane];
    outb[n * HD + 64 + lane] = ob + sc0b[n * HD + 64 + lane];
}

extern "C" void kernel_launch(void* const* d_in, const int* in_sizes, int n_in,
                              void* d_out, int out_size, void* d_ws, size_t ws_size,
                              hipStream_t stream) {
    const float* pos    = (const float*)d_in[0];
    const float* shifts = (const float*)d_in[1];
    const float* na     = (const float*)d_in[2];
    const float* We     = (const float*)d_in[3];
    const float* Wsc1   = (const float*)d_in[4];
    const float* Wup01  = (const float*)d_in[5];
    const float* R10    = (const float*)d_in[6];
    const float* R11    = (const float*)d_in[7];
    const float* R12    = (const float*)d_in[8];
    const float* R13    = (const float*)d_in[9];
    const float* Wout01 = (const float*)d_in[10];
    const float* Wout11 = (const float*)d_in[11];
    const float* Wp01   = (const float*)d_in[12];
    const float* Wp11   = (const float*)d_in[13];
    const float* Wl01   = (const float*)d_in[14];
    const float* Wl11   = (const float*)d_in[15];
    const float* Wsc2   = (const float*)d_in[16];
    const float* Wup02  = (const float*)d_in[17];
    const float* Wup12  = (const float*)d_in[18];
    const float* R20    = (const float*)d_in[19];
    const float* R21    = (const float*)d_in[20];
    const float* R22    = (const float*)d_in[21];
    const float* R23    = (const float*)d_in[22];
    const float* Wout02 = (const float*)d_in[23];
    const float* Wout12 = (const float*)d_in[24];
    const float* Wp02   = (const float*)d_in[25];
    const float* Wl02   = (const float*)d_in[26];
    const int*   idx_i  = (const int*)d_in[27];
    const int*   idx_j  = (const int*)d_in[28];
    float* out = (float*)d_out;

    char* ws = (char*)d_ws;
    size_t off = 0;
    auto alloc = [&](size_t bytes) -> char* {
        char* pp = ws + off;
        off += (bytes + 255) & ~(size_t)255;
        return pp;
    };
    int*   cnt   = (int*)alloc(4);
    float* a0_1  = (float*)alloc((size_t)NN * HD * 4);        // contiguous block of 4 accumulators
    float* a1_1  = (float*)alloc((size_t)NN * HD * 3 * 4);
    float* a0_2  = (float*)alloc((size_t)NN * HD * 4);
    float* a1_2  = (float*)alloc((size_t)NN * HD * 3 * 4);
    int*   act_i = (int*)alloc((size_t)NE * 4);
    int*   act_j = (int*)alloc((size_t)NE * 4);
    float* actY  = (float*)alloc((size_t)NE * 3 * 4);
    float* actF  = (float*)alloc((size_t)NE * NBASIS * 4);
    int*   spec  = (int*)alloc((size_t)NN * 4);
    float* sc0s  = (float*)alloc((size_t)NSPEC * HD * 4);
    float* h0s   = (float*)alloc((size_t)NSPEC * HD * 4);
    float* out1  = (float*)alloc((size_t)NN * HD * 3 * 4);
    float* sc0b  = (float*)alloc((size_t)NN * HD * 4);
    float* g0    = (float*)alloc((size_t)NN * HD * 4);
    float* g1    = (float*)alloc((size_t)NN * HD * 3 * 4);

    // zero the 4 contiguous accumulator arrays (a0_1..a1_2) + counter
    long n4 = (long)NN * HD * 8 / 4;
    k_zero<<<2048, 256, 0, stream>>>((float4*)a0_1, cnt, n4);
    k_species<<<(NN + 255) / 256, 256, 0, stream>>>(na, spec);
    k_tables<<<(NSPEC * HD + 255) / 256, 256, 0, stream>>>(We, Wsc1, Wup01, sc0s, h0s);
    k_compact<<<NE / 256, 256, 0, stream>>>(pos, shifts, idx_i, idx_j, cnt, act_i, act_j, actY, actF);
    k_edge1<<<512, 256, 0, stream>>>(cnt, act_i, act_j, actY, actF, spec,
                                     R10, R11, R12, R13, h0s, a0_1, a1_1);
    k_nodeA<<<NN / 4, 256, 0, stream>>>(a0_1, a1_1, spec, Wout01, Wout11, Wp01, Wp11,
                                        Wl01, Wl11, sc0s, out, out1);
    k_nodeB<<<NN / 4, 256, 0, stream>>>(out, out1, spec, Wsc2, Wup02, Wup12, sc0b, g0, g1);
    k_edge2<<<512, 256, 0, stream>>>(cnt, act_i, act_j, actY, actF,
                                     R20, R21, R22, R23, g0, g1, a0_2, a1_2);
    k_nodeC<<<NN / 4, 256, 0, stream>>>(a0_2, a1_2, spec, Wout02, Wout12, Wp02, Wl02,
                                        sc0b, out + (size_t)NN * HD);
}

// Round 2
// 348.530 us; speedup vs baseline: 1.1505x; 1.1505x over previous
//
#include <hip/hip_runtime.h>
#include <math.h>

#define NN 10000
#define NE 256000
#define HD 128
#define PD 64
#define NBASIS 8
#define NSPEC 10
#define RHID 64
#define RCUT 5.0f
#define INV_AVG 0.0390625f   // 1/25.6 exact
#define PI_F 3.14159265358979f

__device__ __forceinline__ float silu(float x) {
    return x / (1.0f + expf(-x));
}

// ---------------- zero accumulators + counters ----------------
__global__ void k_zero(float4* acc, int* cnt, int* hist, long n4) {
    long i = (long)blockIdx.x * blockDim.x + threadIdx.x;
    if (i == 0) {
        *cnt = 0;
        for (int s = 0; s < NSPEC; s++) hist[s] = 0;
    }
    long stride = (long)gridDim.x * blockDim.x;
    float4 z = make_float4(0.f, 0.f, 0.f, 0.f);
    for (; i < n4; i += stride) acc[i] = z;
}

// ---------------- species id per node + histogram ----------------
__global__ void k_species(const float* __restrict__ na, int* __restrict__ spec, int* hist) {
    int n = blockIdx.x * 256 + threadIdx.x;
    if (n >= NN) return;
    int s = 0;
    for (int k = 0; k < NSPEC; k++)
        if (na[n * NSPEC + k] > 0.5f) s = k;
    spec[n] = s;
    atomicAdd(&hist[s], 1);
}

// ---------------- tiny exclusive scan over 10 species ----------------
__global__ void k_scan(const int* __restrict__ hist, int* __restrict__ basep) {
    if (threadIdx.x == 0) {
        int acc = 0;
        for (int s = 0; s < NSPEC; s++) { basep[s] = acc; acc += hist[s]; }
    }
}

// ---------------- scatter node ids into species-sorted order ----------------
__global__ void k_scatter(const int* __restrict__ spec, int* basep, int* __restrict__ ord) {
    int n = blockIdx.x * 256 + threadIdx.x;
    if (n >= NN) return;
    int pos = atomicAdd(&basep[spec[n]], 1);
    ord[pos] = n;
}

// ---------------- per-species tables: sc0_s, h0_s ----------------
__global__ void k_tables(const float* __restrict__ We, const float* __restrict__ Wsc1,
                         const float* __restrict__ Wup01,
                         float* __restrict__ sc0s, float* __restrict__ h0s) {
    int t = blockIdx.x * 256 + threadIdx.x;
    if (t >= NSPEC * HD) return;
    int s = t / HD, h = t % HD;
    float acc1 = 0.f, acc2 = 0.f;
    for (int c = 0; c < HD; c++) {
        float fe = We[s * HD + c];
        acc1 += fe * Wsc1[(s * HD + c) * HD + h];
        acc2 += fe * Wup01[c * HD + h];
    }
    sc0s[t] = acc1;
    h0s[t] = acc2;
}

// ---------------- edge compaction: geometry + radial basis ----------------
__global__ void k_compact(const float* __restrict__ pos, const float* __restrict__ shifts,
                          const int* __restrict__ ii, const int* __restrict__ jj,
                          int* cnt, int* __restrict__ ai, int* __restrict__ aj,
                          float* __restrict__ aY, float* __restrict__ aF) {
    int e = blockIdx.x * 256 + threadIdx.x;
    if (e >= NE) return;
    int i = ii[e], j = jj[e];
    float vx = pos[i * 3 + 0] - pos[j * 3 + 0] - shifts[e * 3 + 0];
    float vy = pos[i * 3 + 1] - pos[j * 3 + 1] - shifts[e * 3 + 1];
    float vz = pos[i * 3 + 2] - pos[j * 3 + 2] - shifts[e * 3 + 2];
    float r = sqrtf(vx * vx + vy * vy + vz * vz);
    r = fmaxf(r, 1e-9f);
    if (r >= RCUT) return;   // env==0 exactly -> message exactly 0 -> skip
    int slot = atomicAdd(cnt, 1);
    ai[slot] = i; aj[slot] = j;
    float inv = 1.0f / r;
    aY[slot * 3 + 0] = vx * inv;
    aY[slot * 3 + 1] = vy * inv;
    aY[slot * 3 + 2] = vz * inv;
    float u = r * (1.0f / RCUT);
    float u5 = u * u * u * u * u;
    float env = 1.0f - 21.0f * u5 + 35.0f * u5 * u - 15.0f * u5 * u * u;
    float c0 = 0.6324555320336759f * env * inv;  // sqrt(2/RC)
    for (int b = 1; b <= NBASIS; b++)
        aF[slot * NBASIS + b - 1] = c0 * sinf((float)b * PI_F * r * (1.0f / RCUT));
}

// ---------------- layer-1 edge: 4 edges per wave ----------------
__global__ __launch_bounds__(256) void k_edge1(
    const int* __restrict__ cnt, const int* __restrict__ ai, const int* __restrict__ aj,
    const float* __restrict__ aY, const float* __restrict__ aF, const int* __restrict__ spec,
    const float* __restrict__ R0, const float* __restrict__ R1,
    const float* __restrict__ R2, const float* __restrict__ R3,
    const float* __restrict__ h0s, float* __restrict__ a0, float* __restrict__ a1) {
    int lane = threadIdx.x & 63;
    int wid = (blockIdx.x * blockDim.x + threadIdx.x) >> 6;
    int nw = (gridDim.x * blockDim.x) >> 6;
    int nact = *cnt;
    for (int base = wid * 4; base < nact; base += nw * 4) {
        int e[4];
        #pragma unroll
        for (int k = 0; k < 4; k++) { int t = base + k; e[k] = (t < nact) ? t : -1; }
        float x[4];
        {
            float r0v[NBASIS];
            #pragma unroll
            for (int b = 0; b < NBASIS; b++) r0v[b] = R0[b * RHID + lane];
            #pragma unroll
            for (int k = 0; k < 4; k++) {
                int ee = (e[k] < 0) ? base : e[k];
                float acc = 0.f;
                #pragma unroll
                for (int b = 0; b < NBASIS; b++) acc += aF[ee * NBASIS + b] * r0v[b];
                x[k] = silu(acc);
            }
        }
        {
            float acc[4] = {0.f, 0.f, 0.f, 0.f};
            for (int c = 0; c < RHID; c++) {
                float wv = R1[c * RHID + lane];
                #pragma unroll
                for (int k = 0; k < 4; k++) acc[k] += __shfl(x[k], c) * wv;
            }
            #pragma unroll
            for (int k = 0; k < 4; k++) x[k] = silu(acc[k]);
        }
        {
            float acc[4] = {0.f, 0.f, 0.f, 0.f};
            for (int c = 0; c < RHID; c++) {
                float wv = R2[c * RHID + lane];
                #pragma unroll
                for (int k = 0; k < 4; k++) acc[k] += __shfl(x[k], c) * wv;
            }
            #pragma unroll
            for (int k = 0; k < 4; k++) x[k] = silu(acc[k]);
        }
        float w00[4] = {0,0,0,0}, w01[4] = {0,0,0,0}, w10[4] = {0,0,0,0}, w11[4] = {0,0,0,0};
        for (int c = 0; c < RHID; c++) {
            const float* row = R3 + c * (2 * HD);
            float l0 = row[lane], l1 = row[64 + lane], l2 = row[128 + lane], l3 = row[192 + lane];
            #pragma unroll
            for (int k = 0; k < 4; k++) {
                float xc = __shfl(x[k], c);
                w00[k] += xc * l0; w01[k] += xc * l1; w10[k] += xc * l2; w11[k] += xc * l3;
            }
        }
        #pragma unroll
        for (int k = 0; k < 4; k++) {
            if (e[k] < 0) continue;
            int ee = e[k];
            int i = ai[ee], j = aj[ee];
            const float* h0 = h0s + spec[j] * HD;
            float Yx = aY[ee * 3], Yy = aY[ee * 3 + 1], Yz = aY[ee * 3 + 2];
            float h0a = h0[lane], h0b = h0[64 + lane];
            float m0a = w00[k] * h0a * INV_AVG, m0b = w01[k] * h0b * INV_AVG;
            float m1a = w10[k] * h0a * INV_AVG, m1b = w11[k] * h0b * INV_AVG;
            atomicAdd(&a0[i * HD + lane], m0a);
            atomicAdd(&a0[i * HD + 64 + lane], m0b);
            atomicAdd(&a1[(i * HD + lane) * 3 + 0], m1a * Yx);
            atomicAdd(&a1[(i * HD + lane) * 3 + 1], m1a * Yy);
            atomicAdd(&a1[(i * HD + lane) * 3 + 2], m1a * Yz);
            atomicAdd(&a1[(i * HD + 64 + lane) * 3 + 0], m1b * Yx);
            atomicAdd(&a1[(i * HD + 64 + lane) * 3 + 1], m1b * Yy);
            atomicAdd(&a1[(i * HD + 64 + lane) * 3 + 2], m1b * Yz);
        }
    }
}

// ---------------- nodeA: 16 nodes/block, 4 per wave ----------------
__global__ __launch_bounds__(256) void k_nodeA(
    const float* __restrict__ a0, const float* __restrict__ a1, const int* __restrict__ spec,
    const float* __restrict__ Wout0, const float* __restrict__ Wout1,
    const float* __restrict__ Wp0, const float* __restrict__ Wp1,
    const float* __restrict__ Wl0, const float* __restrict__ Wl1,
    const float* __restrict__ sc0s, float* __restrict__ out0, float* __restrict__ out1) {
    __shared__ float sA0[16][HD];
    __shared__ float sA1[16][HD * 3];
    __shared__ float sB0[16][PD];
    __shared__ float sB1[16][3][PD];
    __shared__ int sSpec[16];
    int lane = threadIdx.x & 63, w = threadIdx.x >> 6;
    int nb = blockIdx.x * 16;
    if (threadIdx.x < 16) sSpec[threadIdx.x] = spec[nb + threadIdx.x];
    for (int t = threadIdx.x; t < 16 * HD; t += 256) {
        int k = t >> 7, c = t & 127;
        sA0[k][c] = a0[(size_t)(nb + k) * HD + c];
    }
    for (int t = threadIdx.x; t < 16 * HD * 3; t += 256) {
        int k = t / 384, c = t % 384;
        sA1[k][c] = a1[(size_t)(nb + k) * 384 + c];
    }
    __syncthreads();
    int w4 = w * 4;
    float A0[4] = {0,0,0,0}, A1x[4] = {0,0,0,0}, A1y[4] = {0,0,0,0}, A1z[4] = {0,0,0,0};
    for (int h = 0; h < HD; h++) {
        float w0 = Wout0[h * PD + lane], w1 = Wout1[h * PD + lane];
        #pragma unroll
        for (int k = 0; k < 4; k++) {
            A0[k] += sA0[w4 + k][h] * w0;
            A1x[k] += sA1[w4 + k][h * 3 + 0] * w1;
            A1y[k] += sA1[w4 + k][h * 3 + 1] * w1;
            A1z[k] += sA1[w4 + k][h * 3 + 2] * w1;
        }
    }
    #pragma unroll
    for (int k = 0; k < 4; k++) {
        int s = sSpec[w4 + k];
        float dot = A1x[k] * A1x[k] + A1y[k] * A1y[k] + A1z[k] * A1z[k];
        const float* wp0 = Wp0 + (s * 5) * PD;
        float A02 = A0[k] * A0[k];
        float B0 = wp0[lane] * A0[k] + wp0[PD + lane] * A02 + wp0[2 * PD + lane] * A02 * A0[k] +
                   wp0[3 * PD + lane] * dot + wp0[4 * PD + lane] * A0[k] * dot;
        const float* wp1 = Wp1 + (s * 4) * PD;
        float fac = wp1[lane] + wp1[PD + lane] * A0[k] + wp1[2 * PD + lane] * A02 + wp1[3 * PD + lane] * dot;
        sB0[w4 + k][lane] = B0;
        sB1[w4 + k][0][lane] = fac * A1x[k];
        sB1[w4 + k][1][lane] = fac * A1y[k];
        sB1[w4 + k][2][lane] = fac * A1z[k];
    }
    __syncthreads();
    float o0a[4] = {0,0,0,0}, o0b[4] = {0,0,0,0};
    float o1a[4][3] = {{0}}, o1b[4][3] = {{0}};
    for (int q = 0; q < PD; q++) {
        float wla = Wl0[q * HD + lane], wlb = Wl0[q * HD + 64 + lane];
        float wma = Wl1[q * HD + lane], wmb = Wl1[q * HD + 64 + lane];
        #pragma unroll
        for (int k = 0; k < 4; k++) {
            float b0 = sB0[w4 + k][q];
            o0a[k] += b0 * wla; o0b[k] += b0 * wlb;
            #pragma unroll
            for (int d = 0; d < 3; d++) {
                float b1 = sB1[w4 + k][d][q];
                o1a[k][d] += b1 * wma; o1b[k][d] += b1 * wmb;
            }
        }
    }
    #pragma unroll
    for (int k = 0; k < 4; k++) {
        int n = nb + w4 + k, s = sSpec[w4 + k];
        out0[(size_t)n * HD + lane] = o0a[k] + sc0s[s * HD + lane];
        out0[(size_t)n * HD + 64 + lane] = o0b[k] + sc0s[s * HD + 64 + lane];
        size_t b1 = ((size_t)n * HD + lane) * 3, b2 = ((size_t)n * HD + 64 + lane) * 3;
        #pragma unroll
        for (int d = 0; d < 3; d++) { out1[b1 + d] = o1a[k][d]; out1[b2 + d] = o1b[k][d]; }
    }
}

// ---------------- nodeB: species-sorted, 16 nodes/block, 4 per wave ----------------
__global__ __launch_bounds__(256) void k_nodeB(
    const float* __restrict__ out0, const float* __restrict__ out1,
    const int* __restrict__ ord, const int* __restrict__ spec,
    const float* __restrict__ Wsc2, const float* __restrict__ Wup02, const float* __restrict__ Wup12,
    float* __restrict__ sc0b, float* __restrict__ g0, float* __restrict__ g1) {
    __shared__ float sO0[16][HD];
    __shared__ float sO1[16][HD * 3];
    __shared__ int sNid[16];
    __shared__ int sSpec[16];
    int lane = threadIdx.x & 63, w = threadIdx.x >> 6;
    if (threadIdx.x < 16) {
        int n = ord[blockIdx.x * 16 + threadIdx.x];
        sNid[threadIdx.x] = n;
        sSpec[threadIdx.x] = spec[n];
    }
    __syncthreads();
    for (int t = threadIdx.x; t < 16 * HD; t += 256) {
        int k = t >> 7, c = t & 127;
        sO0[k][c] = out0[(size_t)sNid[k] * HD + c];
    }
    for (int t = threadIdx.x; t < 16 * HD * 3; t += 256) {
        int k = t / 384, c = t % 384;
        sO1[k][c] = out1[(size_t)sNid[k] * 384 + c];
    }
    __syncthreads();
    int w4 = w * 4;
    int sk[4];
    #pragma unroll
    for (int k = 0; k < 4; k++) sk[k] = sSpec[w4 + k];
    bool uni = (sk[0] == sk[1]) && (sk[1] == sk[2]) && (sk[2] == sk[3]);
    float sba[4] = {0,0,0,0}, sbb[4] = {0,0,0,0}, ga[4] = {0,0,0,0}, gb[4] = {0,0,0,0};
    float g1a[4][3] = {{0}}, g1b[4][3] = {{0}};
    if (uni) {
        const float* Ws = Wsc2 + (size_t)sk[0] * HD * HD;
        for (int c = 0; c < HD; c++) {
            float wsa = Ws[c * HD + lane], wsb = Ws[c * HD + 64 + lane];
            float wu0a = Wup02[c * HD + lane], wu0b = Wup02[c * HD + 64 + lane];
            float wu1a = Wup12[c * HD + lane], wu1b = Wup12[c * HD + 64 + lane];
            #pragma unroll
            for (int k = 0; k < 4; k++) {
                float v0 = sO0[w4 + k][c];
                sba[k] += v0 * wsa; sbb[k] += v0 * wsb;
                ga[k] += v0 * wu0a; gb[k] += v0 * wu0b;
                float v1x = sO1[w4 + k][c * 3], v1y = sO1[w4 + k][c * 3 + 1], v1z = sO1[w4 + k][c * 3 + 2];
                g1a[k][0] += v1x * wu1a; g1a[k][1] += v1y * wu1a; g1a[k][2] += v1z * wu1a;
                g1b[k][0] += v1x * wu1b; g1b[k][1] += v1y * wu1b; g1b[k][2] += v1z * wu1b;
            }
        }
    } else {
        for (int c = 0; c < HD; c++) {
            float wu0a = Wup02[c * HD + lane], wu0b = Wup02[c * HD + 64 + lane];
            float wu1a = Wup12[c * HD + lane], wu1b = Wup12[c * HD + 64 + lane];
            #pragma unroll
            for (int k = 0; k < 4; k++) {
                const float* Ws = Wsc2 + (size_t)sk[k] * HD * HD;
                float wsa = Ws[c * HD + lane], wsb = Ws[c * HD + 64 + lane];
                float v0 = sO0[w4 + k][c];
                sba[k] += v0 * wsa; sbb[k] += v0 * wsb;
                ga[k] += v0 * wu0a; gb[k] += v0 * wu0b;
                float v1x = sO1[w4 + k][c * 3], v1y = sO1[w4 + k][c * 3 + 1], v1z = sO1[w4 + k][c * 3 + 2];
                g1a[k][0] += v1x * wu1a; g1a[k][1] += v1y * wu1a; g1a[k][2] += v1z * wu1a;
                g1b[k][0] += v1x * wu1b; g1b[k][1] += v1y * wu1b; g1b[k][2] += v1z * wu1b;
            }
        }
    }
    #pragma unroll
    for (int k = 0; k < 4; k++) {
        int n = sNid[w4 + k];
        sc0b[(size_t)n * HD + lane] = sba[k];
        sc0b[(size_t)n * HD + 64 + lane] = sbb[k];
        g0[(size_t)n * HD + lane] = ga[k];
        g0[(size_t)n * HD + 64 + lane] = gb[k];
        size_t b1 = ((size_t)n * HD + lane) * 3, b2 = ((size_t)n * HD + 64 + lane) * 3;
        #pragma unroll
        for (int d = 0; d < 3; d++) { g1[b1 + d] = g1a[k][d]; g1[b2 + d] = g1b[k][d]; }
    }
}

// ---------------- layer-2 edge: 4 edges per wave ----------------
__global__ __launch_bounds__(256) void k_edge2(
    const int* __restrict__ cnt, const int* __restrict__ ai, const int* __restrict__ aj,
    const float* __restrict__ aY, const float* __restrict__ aF,
    const float* __restrict__ R0, const float* __restrict__ R1,
    const float* __restrict__ R2, const float* __restrict__ R3,
    const float* __restrict__ g0, const float* __restrict__ g1,
    float* __restrict__ a0, float* __restrict__ a1) {
    int lane = threadIdx.x & 63;
    int wid = (blockIdx.x * blockDim.x + threadIdx.x) >> 6;
    int nw = (gridDim.x * blockDim.x) >> 6;
    int nact = *cnt;
    for (int base = wid * 4; base < nact; base += nw * 4) {
        int e[4];
        #pragma unroll
        for (int k = 0; k < 4; k++) { int t = base + k; e[k] = (t < nact) ? t : -1; }
        float x[4];
        {
            float r0v[NBASIS];
            #pragma unroll
            for (int b = 0; b < NBASIS; b++) r0v[b] = R0[b * RHID + lane];
            #pragma unroll
            for (int k = 0; k < 4; k++) {
                int ee = (e[k] < 0) ? base : e[k];
                float acc = 0.f;
                #pragma unroll
                for (int b = 0; b < NBASIS; b++) acc += aF[ee * NBASIS + b] * r0v[b];
                x[k] = silu(acc);
            }
        }
        {
            float acc[4] = {0.f, 0.f, 0.f, 0.f};
            for (int c = 0; c < RHID; c++) {
                float wv = R1[c * RHID + lane];
                #pragma unroll
                for (int k = 0; k < 4; k++) acc[k] += __shfl(x[k], c) * wv;
            }
            #pragma unroll
            for (int k = 0; k < 4; k++) x[k] = silu(acc[k]);
        }
        {
            float acc[4] = {0.f, 0.f, 0.f, 0.f};
            for (int c = 0; c < RHID; c++) {
                float wv = R2[c * RHID + lane];
                #pragma unroll
                for (int k = 0; k < 4; k++) acc[k] += __shfl(x[k], c) * wv;
            }
            #pragma unroll
            for (int k = 0; k < 4; k++) x[k] = silu(acc[k]);
        }
        float wa[4][5] = {{0}}, wb[4][5] = {{0}};
        for (int c = 0; c < RHID; c++) {
            const float* row = R3 + c * (5 * HD);
            float la[5], lb[5];
            #pragma unroll
            for (int q = 0; q < 5; q++) { la[q] = row[q * HD + lane]; lb[q] = row[q * HD + 64 + lane]; }
            #pragma unroll
            for (int k = 0; k < 4; k++) {
                float xc = __shfl(x[k], c);
                #pragma unroll
                for (int q = 0; q < 5; q++) { wa[k][q] += xc * la[q]; wb[k][q] += xc * lb[q]; }
            }
        }
        #pragma unroll
        for (int k = 0; k < 4; k++) {
            if (e[k] < 0) continue;
            int ee = e[k];
            int i = ai[ee], j = aj[ee];
            float Yx = aY[ee * 3], Yy = aY[ee * 3 + 1], Yz = aY[ee * 3 + 2];
            const float* g0j = g0 + (size_t)j * HD;
            const float* g1j = g1 + (size_t)j * HD * 3;
            float gva = g0j[lane], gvb = g0j[64 + lane];
            float gax = g1j[lane * 3], gay = g1j[lane * 3 + 1], gaz = g1j[lane * 3 + 2];
            float gbx = g1j[(64 + lane) * 3], gby = g1j[(64 + lane) * 3 + 1], gbz = g1j[(64 + lane) * 3 + 2];
            float dota = gax * Yx + gay * Yy + gaz * Yz;
            float dotb = gbx * Yx + gby * Yy + gbz * Yz;
            float m0a = (wa[k][0] * gva + wa[k][3] * dota) * INV_AVG;
            float m0b = (wb[k][0] * gvb + wb[k][3] * dotb) * INV_AVG;
            float cax = gay * Yz - gaz * Yy, cay = gaz * Yx - gax * Yz, caz = gax * Yy - gay * Yx;
            float cbx = gby * Yz - gbz * Yy, cby = gbz * Yx - gbx * Yz, cbz = gbx * Yy - gby * Yx;
            float m1ax = (wa[k][1] * gva * Yx + wa[k][2] * gax + wa[k][4] * cax) * INV_AVG;
            float m1ay = (wa[k][1] * gva * Yy + wa[k][2] * gay + wa[k][4] * cay) * INV_AVG;
            float m1az = (wa[k][1] * gva * Yz + wa[k][2] * gaz + wa[k][4] * caz) * INV_AVG;
            float m1bx = (wb[k][1] * gvb * Yx + wb[k][2] * gbx + wb[k][4] * cbx) * INV_AVG;
            float m1by = (wb[k][1] * gvb * Yy + wb[k][2] * gby + wb[k][4] * cby) * INV_AVG;
            float m1bz = (wb[k][1] * gvb * Yz + wb[k][2] * gbz + wb[k][4] * cbz) * INV_AVG;
            atomicAdd(&a0[i * HD + lane], m0a);
            atomicAdd(&a0[i * HD + 64 + lane], m0b);
            atomicAdd(&a1[(i * HD + lane) * 3 + 0], m1ax);
            atomicAdd(&a1[(i * HD + lane) * 3 + 1], m1ay);
            atomicAdd(&a1[(i * HD + lane) * 3 + 2], m1az);
            atomicAdd(&a1[(i * HD + 64 + lane) * 3 + 0], m1bx);
            atomicAdd(&a1[(i * HD + 64 + lane) * 3 + 1], m1by);
            atomicAdd(&a1[(i * HD + 64 + lane) * 3 + 2], m1bz);
        }
    }
}

// ---------------- nodeC: 16 nodes/block, 4 per wave ----------------
__global__ __launch_bounds__(256) void k_nodeC(
    const float* __restrict__ a0, const float* __restrict__ a1, const int* __restrict__ spec,
    const float* __restrict__ Wout0, const float* __restrict__ Wout1,
    const float* __restrict__ Wp0, const float* __restrict__ Wl0,
    const float* __restrict__ sc0b, float* __restrict__ outb) {
    __shared__ float sA0[16][HD];
    __shared__ float sA1[16][HD * 3];
    __shared__ float sB0[16][PD];
    __shared__ int sSpec[16];
    int lane = threadIdx.x & 63, w = threadIdx.x >> 6;
    int nb = blockIdx.x * 16;
    if (threadIdx.x < 16) sSpec[threadIdx.x] = spec[nb + threadIdx.x];
    for (int t = threadIdx.x; t < 16 * HD; t += 256) {
        int k = t >> 7, c = t & 127;
        sA0[k][c] = a0[(size_t)(nb + k) * HD + c];
    }
    for (int t = threadIdx.x; t < 16 * HD * 3; t += 256) {
        int k = t / 384, c = t % 384;
        sA1[k][c] = a1[(size_t)(nb + k) * 384 + c];
    }
    __syncthreads();
    int w4 = w * 4;
    float A0[4] = {0,0,0,0}, A1x[4] = {0,0,0,0}, A1y[4] = {0,0,0,0}, A1z[4] = {0,0,0,0};
    for (int h = 0; h < HD; h++) {
        float w0 = Wout0[h * PD + lane], w1 = Wout1[h * PD + lane];
        #pragma unroll
        for (int k = 0; k < 4; k++) {
            A0[k] += sA0[w4 + k][h] * w0;
            A1x[k] += sA1[w4 + k][h * 3 + 0] * w1;
            A1y[k] += sA1[w4 + k][h * 3 + 1] * w1;
            A1z[k] += sA1[w4 + k][h * 3 + 2] * w1;
        }
    }
    #pragma unroll
    for (int k = 0; k < 4; k++) {
        int s = sSpec[w4 + k];
        float dot = A1x[k] * A1x[k] + A1y[k] * A1y[k] + A1z[k] * A1z[k];
        const float* wp0 = Wp0 + (s * 5) * PD;
        float A02 = A0[k] * A0[k];
        float B0 = wp0[lane] * A0[k] + wp0[PD + lane] * A02 + wp0[2 * PD + lane] * A02 * A0[k] +
                   wp0[3 * PD + lane] * dot + wp0[4 * PD + lane] * A0[k] * dot;
        sB0[w4 + k][lane] = B0;
    }
    __syncthreads();
    float oa[4] = {0,0,0,0}, ob[4] = {0,0,0,0};
    for (int q = 0; q < PD; q++) {
        float wla = Wl0[q * HD + lane], wlb = Wl0[q * HD + 64 + lane];
        #pragma unroll
        for (int k = 0; k < 4; k++) {
            float b0 = sB0[w4 + k][q];
            oa[k] += b0 * wla; ob[k] += b0 * wlb;
        }
    }
    #pragma unroll
    for (int k = 0; k < 4; k++) {
        int n = nb + w4 + k;
        outb[(size_t)n * HD + lane] = oa[k] + sc0b[(size_t)n * HD + lane];
        outb[(size_t)n * HD + 64 + lane] = ob[k] + sc0b[(size_t)n * HD + 64 + lane];
    }
}

extern "C" void kernel_launch(void* const* d_in, const int* in_sizes, int n_in,
                              void* d_out, int out_size, void* d_ws, size_t ws_size,
                              hipStream_t stream) {
    const float* pos    = (const float*)d_in[0];
    const float* shifts = (const float*)d_in[1];
    const float* na     = (const float*)d_in[2];
    const float* We     = (const float*)d_in[3];
    const float* Wsc1   = (const float*)d_in[4];
    const float* Wup01  = (const float*)d_in[5];
    const float* R10    = (const float*)d_in[6];
    const float* R11    = (const float*)d_in[7];
    const float* R12    = (const float*)d_in[8];
    const float* R13    = (const float*)d_in[9];
    const float* Wout01 = (const float*)d_in[10];
    const float* Wout11 = (const float*)d_in[11];
    const float* Wp01   = (const float*)d_in[12];
    const float* Wp11   = (const float*)d_in[13];
    const float* Wl01   = (const float*)d_in[14];
    const float* Wl11   = (const float*)d_in[15];
    const float* Wsc2   = (const float*)d_in[16];
    const float* Wup02  = (const float*)d_in[17];
    const float* Wup12  = (const float*)d_in[18];
    const float* R20    = (const float*)d_in[19];
    const float* R21    = (const float*)d_in[20];
    const float* R22    = (const float*)d_in[21];
    const float* R23    = (const float*)d_in[22];
    const float* Wout02 = (const float*)d_in[23];
    const float* Wout12 = (const float*)d_in[24];
    const float* Wp02   = (const float*)d_in[25];
    const float* Wl02   = (const float*)d_in[26];
    const int*   idx_i  = (const int*)d_in[27];
    const int*   idx_j  = (const int*)d_in[28];
    float* out = (float*)d_out;

    char* ws = (char*)d_ws;
    size_t off = 0;
    auto alloc = [&](size_t bytes) -> char* {
        char* pp = ws + off;
        off += (bytes + 255) & ~(size_t)255;
        return pp;
    };
    int*   cnt   = (int*)alloc(4);
    int*   hist  = (int*)alloc(NSPEC * 4);
    int*   basep = (int*)alloc(NSPEC * 4);
    float* a0_1  = (float*)alloc((size_t)NN * HD * 4);        // contiguous block of 4 accumulators
    float* a1_1  = (float*)alloc((size_t)NN * HD * 3 * 4);
    float* a0_2  = (float*)alloc((size_t)NN * HD * 4);
    float* a1_2  = (float*)alloc((size_t)NN * HD * 3 * 4);
    int*   act_i = (int*)alloc((size_t)NE * 4);
    int*   act_j = (int*)alloc((size_t)NE * 4);
    float* actY  = (float*)alloc((size_t)NE * 3 * 4);
    float* actF  = (float*)alloc((size_t)NE * NBASIS * 4);
    int*   spec  = (int*)alloc((size_t)NN * 4);
    int*   ordn  = (int*)alloc((size_t)NN * 4);
    float* sc0s  = (float*)alloc((size_t)NSPEC * HD * 4);
    float* h0s   = (float*)alloc((size_t)NSPEC * HD * 4);
    float* out1  = (float*)alloc((size_t)NN * HD * 3 * 4);
    float* sc0b  = (float*)alloc((size_t)NN * HD * 4);
    float* g0    = (float*)alloc((size_t)NN * HD * 4);
    float* g1    = (float*)alloc((size_t)NN * HD * 3 * 4);

    long n4 = (long)NN * HD * 8 / 4;
    k_zero<<<2048, 256, 0, stream>>>((float4*)a0_1, cnt, hist, n4);
    k_species<<<(NN + 255) / 256, 256, 0, stream>>>(na, spec, hist);
    k_scan<<<1, 64, 0, stream>>>(hist, basep);
    k_scatter<<<(NN + 255) / 256, 256, 0, stream>>>(spec, basep, ordn);
    k_tables<<<(NSPEC * HD + 255) / 256, 256, 0, stream>>>(We, Wsc1, Wup01, sc0s, h0s);
    k_compact<<<NE / 256, 256, 0, stream>>>(pos, shifts, idx_i, idx_j, cnt, act_i, act_j, actY, actF);
    k_edge1<<<512, 256, 0, stream>>>(cnt, act_i, act_j, actY, actF, spec,
                                     R10, R11, R12, R13, h0s, a0_1, a1_1);
    k_nodeA<<<NN / 16, 256, 0, stream>>>(a0_1, a1_1, spec, Wout01, Wout11, Wp01, Wp11,
                                         Wl01, Wl11, sc0s, out, out1);
    k_nodeB<<<NN / 16, 256, 0, stream>>>(out, out1, ordn, spec, Wsc2, Wup02, Wup12, sc0b, g0, g1);
    k_edge2<<<512, 256, 0, stream>>>(cnt, act_i, act_j, actY, actF,
                                     R20, R21, R22, R23, g0, g1, a0_2, a1_2);
    k_nodeC<<<NN / 16, 256, 0, stream>>>(a0_2, a1_2, spec, Wout02, Wout12, Wp02, Wl02,
                                         sc0b, out + (size_t)NN * HD);
}